// Round 12
// baseline (498.142 us; speedup 1.0000x reference)
//
#include <hip/hip_runtime.h>
#include <hip/hip_bf16.h>
#include <cstdint>
#include <cstddef>

// PoolingAttention.
// R17: kv GEMM + attention FUSED (kills the 229MB kv write + 235MB re-read).
// One block per 2 batches: GEMM M=64(56 real)xN=1024xK=512 with A (pools
// rows) staged once in LDS (XOR swizzle, conflict-free b128) and W_kv read
// DIRECTLY from global -- W is 1MB, L2-resident across all 2048 blocks; no
// ring, no per-step barriers. acc -> LDS kv tile in the verified R10
// attention layout (2KB rows, K|V halves, x(row) swizzle; x(bb*32+m)==x(m)),
// pad rows zeroed, then R10 per-wave attention (wave=head, 2 tasks).
// GEMM structure postscript: 10 schedule/tile variants all landed 164-185us
// (R6-R16); intra-GEMM optimization exhausted, so remove the round trip.
// q/proj GEMMs: R6 core (256x256, 8 waves, BK=32 ring-4, counted vmcnt(4),
// T2 source-preswizzle, XCD grid). pools_ln/convert unchanged.
// Pipeline: convert(W*) -> pools_ln(+xb) -> GEMM(q) -> FUSED(kv+attn) -> GEMM(proj)+bias

using bf16 = __hip_bfloat16;

#define B_SZ   4096
#define NTOK   16
#define CDIM   512
#define MPOOL  28
#define NHEAD  8
#define HDIM   64
#define LN_EPS 1e-5f
#define ATT_SCALE 0.125f

typedef short bf16x8 __attribute__((ext_vector_type(8)));
typedef float f32x4  __attribute__((ext_vector_type(4)));

__constant__ int c_g1[16] = {2,3,5,6,1,4,0,7,8,9,14,15,11,12,10,13};
__constant__ int c_g2[8]  = {0,1,2,3,5,6,4,7};

__device__ __forceinline__ unsigned short f2b(float f) {
    unsigned u = __float_as_uint(f);
    return (unsigned short)((u + 0x7FFFu + ((u >> 16) & 1u)) >> 16);
}

// async global->LDS, 16B per lane; LDS dest is wave-uniform base (+lane*16 by HW)
__device__ __forceinline__ void lds_cp16(const void* g, void* l) {
    __builtin_amdgcn_global_load_lds(
        (const __attribute__((address_space(1))) void*)g,
        (__attribute__((address_space(3))) void*)l, 16, 0, 0);
}

// ---------------------------------------------------------------------------
// fp32 -> bf16 convert for all three weight tensors in one launch.
// blocks [0,128): w_q (32768 x8); [128,384): w_kv (65536); [384,512): w_proj.
// ---------------------------------------------------------------------------
__global__ __launch_bounds__(256) void convert_all_kernel(
    const float* __restrict__ w_q, const float* __restrict__ w_kv,
    const float* __restrict__ w_proj, bf16* __restrict__ wqb,
    bf16* __restrict__ wkvb, bf16* __restrict__ wpb)
{
    const float* src; bf16* dst; int i;
    const int blk = blockIdx.x;
    if (blk < 128)      { src = w_q;    dst = wqb; i = blk * 256 + threadIdx.x; }
    else if (blk < 384) { src = w_kv;   dst = wkvb; i = (blk - 128) * 256 + threadIdx.x; }
    else                { src = w_proj; dst = wpb; i = (blk - 384) * 256 + threadIdx.x; }
    const float4* p = (const float4*)(src + (size_t)i * 8);
    float4 a = p[0], b = p[1];
    uint4 pk;
    pk.x = (unsigned)f2b(a.x) | ((unsigned)f2b(a.y) << 16);
    pk.y = (unsigned)f2b(a.z) | ((unsigned)f2b(a.w) << 16);
    pk.z = (unsigned)f2b(b.x) | ((unsigned)f2b(b.y) << 16);
    pk.w = (unsigned)f2b(b.z) | ((unsigned)f2b(b.w) << 16);
    *(uint4*)(dst + (size_t)i * 8) = pk;
}

// ---------------------------------------------------------------------------
// Kernel 1: pools + LayerNorm (one wave per row); m<16 waves also emit raw-x bf16.
// ---------------------------------------------------------------------------
__global__ __launch_bounds__(256) void pools_ln_kernel(
    const float* __restrict__ x, const float* __restrict__ gamma,
    const float* __restrict__ beta, bf16* __restrict__ pools,
    bf16* __restrict__ xb)
{
    const int wave = threadIdx.x >> 6;
    const int lane = threadIdx.x & 63;
    const int row  = blockIdx.x * 4 + wave;          // 0 .. B*28-1 (exact)
    const int b = row / MPOOL;
    const int m = row % MPOOL;
    const float* xb_src = x + (size_t)b * NTOK * CDIM;
    const int c0 = lane * 8;

    float v[8];
    if (m < 16) {
        const float4* p = (const float4*)(xb_src + m * CDIM + c0);
        float4 a = p[0], c = p[1];
        v[0]=a.x; v[1]=a.y; v[2]=a.z; v[3]=a.w;
        v[4]=c.x; v[5]=c.y; v[6]=c.z; v[7]=c.w;
        uint4 pk;
        pk.x = (unsigned)f2b(v[0]) | ((unsigned)f2b(v[1]) << 16);
        pk.y = (unsigned)f2b(v[2]) | ((unsigned)f2b(v[3]) << 16);
        pk.z = (unsigned)f2b(v[4]) | ((unsigned)f2b(v[5]) << 16);
        pk.w = (unsigned)f2b(v[6]) | ((unsigned)f2b(v[7]) << 16);
        *(uint4*)(xb + (size_t)b * NTOK * CDIM + (size_t)m * CDIM + c0) = pk;
    } else {
        int r0, r1;
        if (m < 24) { int j = m - 16; r0 = c_g1[2*j]; r1 = c_g1[2*j+1]; }
        else        { int j = m - 24; r0 = c_g2[2*j]; r1 = c_g2[2*j+1]; }
        const float4* p0 = (const float4*)(xb_src + r0 * CDIM + c0);
        const float4* p1 = (const float4*)(xb_src + r1 * CDIM + c0);
        float4 a0 = p0[0], a1 = p0[1];
        float4 b0 = p1[0], b1 = p1[1];
        v[0]=0.5f*(a0.x+b0.x); v[1]=0.5f*(a0.y+b0.y);
        v[2]=0.5f*(a0.z+b0.z); v[3]=0.5f*(a0.w+b0.w);
        v[4]=0.5f*(a1.x+b1.x); v[5]=0.5f*(a1.y+b1.y);
        v[6]=0.5f*(a1.z+b1.z); v[7]=0.5f*(a1.w+b1.w);
    }

    float s = 0.f, sq = 0.f;
#pragma unroll
    for (int j = 0; j < 8; ++j) { s += v[j]; sq += v[j]*v[j]; }
#pragma unroll
    for (int off = 1; off < 64; off <<= 1) {
        s  += __shfl_xor(s,  off, 64);
        sq += __shfl_xor(sq, off, 64);
    }
    const float mu   = s * (1.f / CDIM);
    const float var  = sq * (1.f / CDIM) - mu * mu;
    const float rstd = rsqrtf(var + LN_EPS);

    unsigned short o[8];
#pragma unroll
    for (int j = 0; j < 8; ++j) {
        float g  = gamma[c0 + j];
        float bb = beta[c0 + j];
        o[j] = f2b((v[j] - mu) * rstd * g + bb);
    }
    uint4 pk;
    pk.x = (unsigned)o[0] | ((unsigned)o[1] << 16);
    pk.y = (unsigned)o[2] | ((unsigned)o[3] << 16);
    pk.z = (unsigned)o[4] | ((unsigned)o[5] << 16);
    pk.w = (unsigned)o[6] | ((unsigned)o[7] << 16);
    *(uint4*)(pools + (size_t)row * CDIM + c0) = pk;
}

// ---------------------------------------------------------------------------
// Kernel 2: bf16 MFMA GEMM  C[M,N] = A[M,K] * W[N,K]^T (+bias), K=512.
// R6 core (q / proj): 256x256 tile, 512 threads = 8 waves (2Mx4N), wave out
// 128x64 (8x4 frags of 16x16x32). BK=32. LDS ring: 4 slots x 32KB = 128KB.
// Stage tile t+2 while computing t; counted vmcnt(4) before each s_barrier.
// T2 swizzle: lds_byte ^= ((lds_byte>>7)&3)<<4 via pre-swizzled global source
// + swizzled ds_read. Grid: XCD-swizzled, N-fastest.
// ---------------------------------------------------------------------------
template<bool OUT_BF16, bool BIAS, int NBLK>
__global__ __launch_bounds__(512, 2) void gemm256_kernel(
    const bf16* __restrict__ A, const bf16* __restrict__ W,
    const float* __restrict__ bias, void* __restrict__ Cptr, int Ncols)
{
    constexpr int K  = 512;
    constexpr int NT = K / 32;              // 16 K-tiles
    extern __shared__ __align__(16) char ring[];   // 4 x 32768 bytes

    const int tid = threadIdx.x;
    const int wv = tid >> 6, ln = tid & 63;
    const int wr = wv >> 2, wc = wv & 3;    // wave grid 2 (M) x 4 (N)
    const int fr = ln & 15, kb = ln >> 4;

    const int p  = blockIdx.x;
    const int o  = p >> 3;
    const int mb = (o / NBLK) * 8 + (p & 7);
    const int nb = o % NBLK;
    const size_t m0 = (size_t)mb * 256;
    const size_t n0 = (size_t)nb * 256;

    // ---- staging (per wave: 2 instrs A + 2 instrs B per K-tile) ----
    const int srow = wv * 16 + (ln >> 2);
    const int scol = (((ln & 3) * 16) ^ (((ln >> 3) & 3) << 4)) >> 1;  // elems
    const bf16* Asrc0 = A + (m0 + srow) * K + scol;
    const bf16* Asrc1 = A + (m0 + 128 + srow) * K + scol;
    const bf16* Wsrc0 = W + (n0 + srow) * K + scol;
    const bf16* Wsrc1 = W + (n0 + 128 + srow) * K + scol;
    char* const ringc = ring;

    // ---- fragment read addresses (region-local, swizzled) ----
    const int aswz  = ((fr >> 1) & 3) << 4;
    const int a_off = (wr * 128 + fr) * 64 + ((kb * 16) ^ aswz);
    const int b_off = 16384 + (wc * 64 + fr) * 64 + ((kb * 16) ^ aswz);

    f32x4 acc[8][4];
#pragma unroll
    for (int i = 0; i < 8; ++i)
#pragma unroll
    for (int j = 0; j < 4; ++j)
        acc[i][j] = f32x4{0.f, 0.f, 0.f, 0.f};

    auto STAGE = [&](int t) {
        char* base = ringc + (t & 3) * 32768 + wv * 1024;
        const int ko = t * 32;
        lds_cp16(Asrc0 + ko, base);
        lds_cp16(Asrc1 + ko, base + 8192);
        lds_cp16(Wsrc0 + ko, base + 16384);
        lds_cp16(Wsrc1 + ko, base + 16384 + 8192);
    };

    STAGE(0);
    STAGE(1);
    asm volatile("s_waitcnt vmcnt(4)" ::: "memory");
    __builtin_amdgcn_s_barrier();

#pragma unroll 1
    for (int t = 0; t < NT; ++t) {
        if (t + 2 < NT) STAGE(t + 2);
        const char* sa = ringc + (t & 3) * 32768;

        bf16x8 af[8], bfr[4];
#pragma unroll
        for (int mi = 0; mi < 8; ++mi)
            af[mi] = *(const bf16x8*)(sa + a_off + mi * 1024);
#pragma unroll
        for (int nj = 0; nj < 4; ++nj)
            bfr[nj] = *(const bf16x8*)(sa + b_off + nj * 1024);

#pragma unroll
        for (int mi = 0; mi < 8; ++mi)
#pragma unroll
        for (int nj = 0; nj < 4; ++nj)
            acc[mi][nj] = __builtin_amdgcn_mfma_f32_16x16x32_bf16(
                af[mi], bfr[nj], acc[mi][nj], 0, 0, 0);

        if (t + 2 < NT) { asm volatile("s_waitcnt vmcnt(4)" ::: "memory"); }
        else            { asm volatile("s_waitcnt vmcnt(0)" ::: "memory"); }
        __builtin_amdgcn_s_barrier();
    }

    // epilogue: C row = m0 + wr*128 + mi*16 + kb*4 + r ; col = n0 + wc*64 + nj*16 + fr
    const int orow0 = wr * 128 + kb * 4;
    const int ocol0 = wc * 64 + fr;
    float bv[4];
#pragma unroll
    for (int nj = 0; nj < 4; ++nj)
        bv[nj] = BIAS ? bias[n0 + ocol0 + nj * 16] : 0.f;
#pragma unroll
    for (int mi = 0; mi < 8; ++mi) {
        const size_t rbase = m0 + orow0 + mi * 16;
#pragma unroll
        for (int r = 0; r < 4; ++r) {
            const size_t rowoff = (rbase + r) * (size_t)Ncols + n0 + ocol0;
#pragma unroll
            for (int nj = 0; nj < 4; ++nj) {
                float v = acc[mi][nj][r] + bv[nj];
                if (OUT_BF16)
                    ((unsigned short*)Cptr)[rowoff + nj * 16] = f2b(v);
                else
                    ((float*)Cptr)[rowoff + nj * 16] = v;
            }
        }
    }
}

// ---------------------------------------------------------------------------
// Kernel 3: FUSED kv-GEMM + attention. One block per 2 batches, 512 thr = 8 waves.
// Phase 1: stage A = pools rows [b0*28, b0*28+64) into LDS [0,64KB) (1KB rows,
//   x(row)=((row&7)<<4)^(((row>>3)&3)<<5) via pre-swizzled source; b128 reads
//   are ~2-way conflict-free -- same algebra as the verified attention stage).
//   Rows 56-63 are neighbor-batch/qbuf data (finite); their outputs are unused.
// Phase 2: GEMM C[64][1024] = A @ W_kv^T. 8 waves, wave wv owns cols
//   [wv*128,+128): 4x8 frags of 16x16x32, acc 128 VGPR. W read DIRECTLY from
//   global (1MB, L2-resident chip-wide). NO ring, NO per-step barriers.
// Phase 3: acc -> LDS kv tile [0,128KB): 2 batches x 32 rows x 2KB (K|V
//   halves), byte = lrow*2048 + (col*2 ^ x(lrow)); x(bb*32+m)==x(m) so the
//   R10 attention read algebra applies unchanged. Pad rows 28-31/60-63 zeroed.
// Phase 4: R10 per-wave attention, wave = head, loop over bb=0,1.
// LDS: 128KB kv + 8KB P_t = 136KB -> 1 block/CU.
// ---------------------------------------------------------------------------
__global__ __launch_bounds__(512, 2) void kvattn_kernel(
    const bf16* __restrict__ pools, const bf16* __restrict__ wkv,
    const bf16* __restrict__ q, bf16* __restrict__ att)
{
    extern __shared__ __align__(16) char smem[];
    const int tid = threadIdx.x;
    const int wv = tid >> 6, ln = tid & 63;
    const int fr = ln & 15, kb = ln >> 4;
    const int b0 = blockIdx.x * 2;

    // ---- Phase 1: stage A (64 rows x 1KB, swizzled source) ----
    const char* Ag = (const char*)(pools + (size_t)b0 * MPOOL * CDIM);
#pragma unroll
    for (int i = 0; i < 8; ++i) {
        const int row = wv * 8 + i;
        const int x   = ((row & 7) << 4) ^ (((row >> 3) & 3) << 5);
        lds_cp16(Ag + (size_t)row * 1024 + ((ln * 16) ^ x), smem + row * 1024);
    }
    __syncthreads();

    // ---- Phase 2: GEMM, W from global ----
    const int n0w = wv * 128;                 // wave's kv-col base
    f32x4 acc[4][8];
#pragma unroll
    for (int i = 0; i < 4; ++i)
#pragma unroll
    for (int j = 0; j < 8; ++j)
        acc[i][j] = f32x4{0.f, 0.f, 0.f, 0.f};

    const bf16* Wl = wkv + (size_t)(n0w + fr) * CDIM + kb * 8;

#pragma unroll
    for (int t = 0; t < 16; ++t) {
        bf16x8 bfr[8], af[4];
#pragma unroll
        for (int nj = 0; nj < 8; ++nj)
            bfr[nj] = *(const bf16x8*)(Wl + (size_t)nj * 16 * CDIM + t * 32);
#pragma unroll
        for (int mi = 0; mi < 4; ++mi) {
            const int row = mi * 16 + fr;
            const int x   = ((row & 7) << 4) ^ (((row >> 3) & 3) << 5);
            af[mi] = *(const bf16x8*)(smem + row * 1024 +
                          ((t * 64 + kb * 16) ^ x));
        }
#pragma unroll
        for (int mi = 0; mi < 4; ++mi)
#pragma unroll
        for (int nj = 0; nj < 8; ++nj)
            acc[mi][nj] = __builtin_amdgcn_mfma_f32_16x16x32_bf16(
                af[mi], bfr[nj], acc[mi][nj], 0, 0, 0);
    }
    __syncthreads();   // all A reads done; region reused for kv tile

    // ---- Phase 3: acc -> LDS kv tile (swizzled), zero pads ----
#pragma unroll
    for (int mi = 0; mi < 4; ++mi) {
#pragma unroll
        for (int r = 0; r < 4; ++r) {
            const int rc = mi * 16 + kb * 4 + r;     // C row (0..63)
            if (rc < 2 * MPOOL) {
                const int bb   = (rc >= MPOOL);
                const int m    = rc - bb * MPOOL;
                const int lrow = bb * 32 + m;
                const int x    = ((lrow & 7) << 4) ^ (((lrow >> 3) & 3) << 5);
                char* dst = smem + lrow * 2048;
#pragma unroll
                for (int nj = 0; nj < 8; ++nj) {
                    const int col = n0w + nj * 16 + fr;
                    *(unsigned short*)(dst + ((col * 2) ^ x)) =
                        f2b(acc[mi][nj][r]);
                }
            }
        }
    }
    // zero pad rows {28..31, 60..63} (16KB = 1024 x 16B over 512 thr x 2)
#pragma unroll
    for (int z = 0; z < 2; ++z) {
        const int e    = z * 512 + tid;       // 0..1023
        const int rr   = e >> 7;              // 0..7
        const int ro   = (e & 127) * 16;
        const int lrow = (rr < 4) ? (28 + rr) : (56 + rr);
        *(uint4*)(smem + lrow * 2048 + ro) = uint4{0u, 0u, 0u, 0u};
    }
    __syncthreads();

    // ---- Phase 4: attention (wave = head h = wv; 2 batch-tasks) ----
    unsigned short* P_t = (unsigned short*)(smem + 131072) + wv * 512;
    const int h = wv;

#pragma unroll 1
    for (int bb = 0; bb < 2; ++bb) {
        const char* kvl = smem + bb * 65536;   // 32 rows x 2KB

        const bf16* qb = q + (size_t)(b0 + bb) * (NTOK * CDIM) + h * HDIM;
        bf16x8 aq[2];                 // Q[fr][ks*32 + kb*8 + j]
#pragma unroll
        for (int ks = 0; ks < 2; ++ks)
            aq[ks] = *(const bf16x8*)(qb + fr * CDIM + ks * 32 + kb * 8);

        bf16x8 bk[2][2];              // K[mt*16+fr][ks*32 + kb*8 + j]
#pragma unroll
        for (int mt = 0; mt < 2; ++mt) {
            const int row = mt * 16 + fr;
            const int x   = ((row & 7) << 4) ^ (((row >> 3) & 3) << 5);
#pragma unroll
            for (int ks = 0; ks < 2; ++ks)
                bk[mt][ks] = *(const bf16x8*)(kvl + row * 2048 +
                                  ((h * 128 + ks * 64 + kb * 16) ^ x));
        }

        bf16x8 bv[4];                 // bv[dt][j] = V[kb*8+j][dt*16+fr]
#pragma unroll
        for (int dt = 0; dt < 4; ++dt)
#pragma unroll
            for (int j = 0; j < 8; ++j) {
                const int row = kb * 8 + j;
                const int x   = ((row & 7) << 4) ^ (((row >> 3) & 3) << 5);
                bv[dt][j] = *(const short*)(kvl + row * 2048 +
                                  ((1024 + h * 128 + dt * 32 + fr * 2) ^ x));
            }

        f32x4 st0 = {0.f, 0.f, 0.f, 0.f}, st1 = {0.f, 0.f, 0.f, 0.f};
        st0 = __builtin_amdgcn_mfma_f32_16x16x32_bf16(aq[0], bk[0][0], st0, 0, 0, 0);
        st0 = __builtin_amdgcn_mfma_f32_16x16x32_bf16(aq[1], bk[0][1], st0, 0, 0, 0);
        st1 = __builtin_amdgcn_mfma_f32_16x16x32_bf16(aq[0], bk[1][0], st1, 0, 0, 0);
        st1 = __builtin_amdgcn_mfma_f32_16x16x32_bf16(aq[1], bk[1][1], st1, 0, 0, 0);

        const bool kmask = (fr >= MPOOL - 16);
#pragma unroll
        for (int r = 0; r < 4; ++r) {
            st0[r] *= ATT_SCALE;
            st1[r] = kmask ? -1e30f : st1[r] * ATT_SCALE;
        }

        float p0[4], p1[4];
#pragma unroll
        for (int r = 0; r < 4; ++r) {
            float mx = fmaxf(st0[r], st1[r]);
            mx = fmaxf(mx, __shfl_xor(mx, 1, 64));
            mx = fmaxf(mx, __shfl_xor(mx, 2, 64));
            mx = fmaxf(mx, __shfl_xor(mx, 4, 64));
            mx = fmaxf(mx, __shfl_xor(mx, 8, 64));
            float e0 = expf(st0[r] - mx);
            float e1 = expf(st1[r] - mx);    // == 0 for masked lanes
            float s = e0 + e1;
            s += __shfl_xor(s, 1, 64);
            s += __shfl_xor(s, 2, 64);
            s += __shfl_xor(s, 4, 64);
            s += __shfl_xor(s, 8, 64);
            const float inv = 1.f / s;
            p0[r] = e0 * inv;
            p1[r] = e1 * inv;
        }

        // transpose P via per-wave P_t (in-wave DS ordering; lgkmcnt guards)
        {
            ushort4 w0, w1;
            w0.x = f2b(p0[0]); w0.y = f2b(p0[1]); w0.z = f2b(p0[2]); w0.w = f2b(p0[3]);
            w1.x = f2b(p1[0]); w1.y = f2b(p1[1]); w1.z = f2b(p1[2]); w1.w = f2b(p1[3]);
            *(ushort4*)&P_t[(fr)      * 16 + kb * 4] = w0;
            *(ushort4*)&P_t[(16 + fr) * 16 + kb * 4] = w1;
        }
        asm volatile("s_waitcnt lgkmcnt(0)" ::: "memory");

        bf16x8 pa;                    // A-frag: P[n=fr][m=kb*8+j]
#pragma unroll
        for (int j = 0; j < 8; ++j)
            pa[j] = (short)P_t[(kb * 8 + j) * 16 + fr];
        asm volatile("s_waitcnt lgkmcnt(0)" ::: "memory");

        f32x4 o[4];
#pragma unroll
        for (int dt = 0; dt < 4; ++dt) {
            o[dt] = f32x4{0.f, 0.f, 0.f, 0.f};
            o[dt] = __builtin_amdgcn_mfma_f32_16x16x32_bf16(pa, bv[dt], o[dt], 0, 0, 0);
        }

        unsigned short* ob = (unsigned short*)(att +
            (size_t)(b0 + bb) * (NTOK * CDIM) + h * HDIM);
#pragma unroll
        for (int r = 0; r < 4; ++r) {
            const size_t nrow = (size_t)(kb * 4 + r) * CDIM;
#pragma unroll
            for (int dt = 0; dt < 4; ++dt)
                ob[nrow + dt * 16 + fr] = f2b(o[dt][r]);
        }
    }
}

// ---------------------------------------------------------------------------
extern "C" void kernel_launch(void* const* d_in, const int* in_sizes, int n_in,
                              void* d_out, int out_size, void* d_ws, size_t ws_size,
                              hipStream_t stream)
{
    const float* x      = (const float*)d_in[0];
    const float* w_q    = (const float*)d_in[1];
    const float* w_kv   = (const float*)d_in[2];
    const float* w_proj = (const float*)d_in[3];
    const float* b_proj = (const float*)d_in[4];
    const float* gamma  = (const float*)d_in[5];
    const float* beta   = (const float*)d_in[6];

    char* ws = (char*)d_ws;
    bf16* xb    = (bf16*)(ws);
    bf16* pools = (bf16*)(ws + 67108864ull);
    bf16* qbuf  = (bf16*)(ws + 67108864ull + 117440512ull);
    bf16* wqb   = (bf16*)(ws + 67108864ull + 117440512ull + 67108864ull + 234881024ull);
    bf16* wkvb  = (bf16*)((char*)wqb + 524288ull);
    bf16* wpb   = (bf16*)((char*)wkvb + 1048576ull);
    bf16* atbuf = pools;   // alias: pools rows consumed before att write?
    // NOTE: fused kernel reads pools rows of batches b0..b0+1 (+8 rows over)
    // and writes att rows of the SAME batches -- but att aliases pools at
    // DIFFERENT addresses (att row = b*16KB*... vs pools b*28KB...). Overlap
    // hazard: block X's att writes could land in pools rows block Y hasn't
    // read yet. UNSAFE -> give att its own buffer (workspace is large).
    bf16* attb  = (bf16*)(ws + 67108864ull + 117440512ull + 67108864ull + 100663296ull);

    hipFuncSetAttribute((const void*)gemm256_kernel<true, false, 2>,
                        hipFuncAttributeMaxDynamicSharedMemorySize, 131072);
    hipFuncSetAttribute((const void*)gemm256_kernel<false, true, 2>,
                        hipFuncAttributeMaxDynamicSharedMemorySize, 131072);
    hipFuncSetAttribute((const void*)kvattn_kernel,
                        hipFuncAttributeMaxDynamicSharedMemorySize, 139264);

    // 0) weight converts (single launch: w_q | w_kv | w_proj)
    convert_all_kernel<<<512, 256, 0, stream>>>(w_q, w_kv, w_proj, wqb, wkvb, wpb);

    // 1) pools + LN (+ xb emission)
    pools_ln_kernel<<<(B_SZ * MPOOL) / 4, 256, 0, stream>>>(x, gamma, beta, pools, xb);

    // 2) q = x @ w_q^T   (65536 x 512 x 512): MB=256, NBLK=2 -> grid 512
    gemm256_kernel<true, false, 2><<<512, 512, 131072, stream>>>(
        xb, wqb, nullptr, (void*)qbuf, 512);

    // 3+4) fused kv GEMM + attention: one block per 2 batches
    kvattn_kernel<<<B_SZ / 2, 512, 139264, stream>>>(pools, wkvb, qbuf, attb);

    // 5) out = att @ w_proj^T + b_proj  (65536 x 512 x 512), fp32 out
    gemm256_kernel<false, true, 2><<<512, 512, 131072, stream>>>(
        attb, wpb, b_proj, d_out, 512);
}

// Round 13
// 418.140 us; speedup vs baseline: 1.1913x; 1.1913x over previous
//
#include <hip/hip_runtime.h>
#include <hip/hip_bf16.h>
#include <cstdint>
#include <cstddef>

// PoolingAttention.
// R18: revert to R14 (session best, 419.05us). R17's kv+attn fusion regressed
// (351us fused vs 264us separate: W-from-global B-frags latency-bound at
// 1 block/CU, no prefetch pipeline -- MfmaUtil 16.8%). Ledger: 10 GEMM
// schedule/tile variants all 164-185us; attention split (R15) neutral;
// fusion (R17) negative. This configuration is the measured optimum.
// R14: kv GEMM on 32x32x16 MFMA frags (R11: kv 169->164us; accepted 4-way
// LDS aliasing), q/proj on 16x16x32 (0 conflicts); single convert launch.
// GEMM core: 256x256 8-wave BK=32 ring-4, counted vmcnt(4), raw s_barrier,
// T2 source-preswizzle, XCD-swizzled grid.
// R10: per-batch LDS attention (8 waves = 8 heads share staged kv slab).
// Pipeline: convert(W*) -> pools_ln(+xb) -> GEMM(q) -> GEMM(kv) -> attention -> GEMM(proj)+bias

using bf16 = __hip_bfloat16;

#define B_SZ   4096
#define NTOK   16
#define CDIM   512
#define MPOOL  28
#define NHEAD  8
#define HDIM   64
#define LN_EPS 1e-5f
#define ATT_SCALE 0.125f

typedef short bf16x8 __attribute__((ext_vector_type(8)));
typedef float f32x4  __attribute__((ext_vector_type(4)));
typedef float f32x16 __attribute__((ext_vector_type(16)));

__constant__ int c_g1[16] = {2,3,5,6,1,4,0,7,8,9,14,15,11,12,10,13};
__constant__ int c_g2[8]  = {0,1,2,3,5,6,4,7};

__device__ __forceinline__ unsigned short f2b(float f) {
    unsigned u = __float_as_uint(f);
    return (unsigned short)((u + 0x7FFFu + ((u >> 16) & 1u)) >> 16);
}

// async global->LDS, 16B per lane; LDS dest is wave-uniform base (+lane*16 by HW)
__device__ __forceinline__ void lds_cp16(const void* g, void* l) {
    __builtin_amdgcn_global_load_lds(
        (const __attribute__((address_space(1))) void*)g,
        (__attribute__((address_space(3))) void*)l, 16, 0, 0);
}

// ---------------------------------------------------------------------------
// fp32 -> bf16 convert for all three weight tensors in one launch.
// blocks [0,128): w_q (32768 x8); [128,384): w_kv (65536); [384,512): w_proj.
// ---------------------------------------------------------------------------
__global__ __launch_bounds__(256) void convert_all_kernel(
    const float* __restrict__ w_q, const float* __restrict__ w_kv,
    const float* __restrict__ w_proj, bf16* __restrict__ wqb,
    bf16* __restrict__ wkvb, bf16* __restrict__ wpb)
{
    const float* src; bf16* dst; int i;
    const int blk = blockIdx.x;
    if (blk < 128)      { src = w_q;    dst = wqb; i = blk * 256 + threadIdx.x; }
    else if (blk < 384) { src = w_kv;   dst = wkvb; i = (blk - 128) * 256 + threadIdx.x; }
    else                { src = w_proj; dst = wpb; i = (blk - 384) * 256 + threadIdx.x; }
    const float4* p = (const float4*)(src + (size_t)i * 8);
    float4 a = p[0], b = p[1];
    uint4 pk;
    pk.x = (unsigned)f2b(a.x) | ((unsigned)f2b(a.y) << 16);
    pk.y = (unsigned)f2b(a.z) | ((unsigned)f2b(a.w) << 16);
    pk.z = (unsigned)f2b(b.x) | ((unsigned)f2b(b.y) << 16);
    pk.w = (unsigned)f2b(b.z) | ((unsigned)f2b(b.w) << 16);
    *(uint4*)(dst + (size_t)i * 8) = pk;
}

// ---------------------------------------------------------------------------
// Kernel 1: pools + LayerNorm (one wave per row); m<16 waves also emit raw-x bf16.
// ---------------------------------------------------------------------------
__global__ __launch_bounds__(256) void pools_ln_kernel(
    const float* __restrict__ x, const float* __restrict__ gamma,
    const float* __restrict__ beta, bf16* __restrict__ pools,
    bf16* __restrict__ xb)
{
    const int wave = threadIdx.x >> 6;
    const int lane = threadIdx.x & 63;
    const int row  = blockIdx.x * 4 + wave;          // 0 .. B*28-1 (exact)
    const int b = row / MPOOL;
    const int m = row % MPOOL;
    const float* xb_src = x + (size_t)b * NTOK * CDIM;
    const int c0 = lane * 8;

    float v[8];
    if (m < 16) {
        const float4* p = (const float4*)(xb_src + m * CDIM + c0);
        float4 a = p[0], c = p[1];
        v[0]=a.x; v[1]=a.y; v[2]=a.z; v[3]=a.w;
        v[4]=c.x; v[5]=c.y; v[6]=c.z; v[7]=c.w;
        uint4 pk;
        pk.x = (unsigned)f2b(v[0]) | ((unsigned)f2b(v[1]) << 16);
        pk.y = (unsigned)f2b(v[2]) | ((unsigned)f2b(v[3]) << 16);
        pk.z = (unsigned)f2b(v[4]) | ((unsigned)f2b(v[5]) << 16);
        pk.w = (unsigned)f2b(v[6]) | ((unsigned)f2b(v[7]) << 16);
        *(uint4*)(xb + (size_t)b * NTOK * CDIM + (size_t)m * CDIM + c0) = pk;
    } else {
        int r0, r1;
        if (m < 24) { int j = m - 16; r0 = c_g1[2*j]; r1 = c_g1[2*j+1]; }
        else        { int j = m - 24; r0 = c_g2[2*j]; r1 = c_g2[2*j+1]; }
        const float4* p0 = (const float4*)(xb_src + r0 * CDIM + c0);
        const float4* p1 = (const float4*)(xb_src + r1 * CDIM + c0);
        float4 a0 = p0[0], a1 = p0[1];
        float4 b0 = p1[0], b1 = p1[1];
        v[0]=0.5f*(a0.x+b0.x); v[1]=0.5f*(a0.y+b0.y);
        v[2]=0.5f*(a0.z+b0.z); v[3]=0.5f*(a0.w+b0.w);
        v[4]=0.5f*(a1.x+b1.x); v[5]=0.5f*(a1.y+b1.y);
        v[6]=0.5f*(a1.z+b1.z); v[7]=0.5f*(a1.w+b1.w);
    }

    float s = 0.f, sq = 0.f;
#pragma unroll
    for (int j = 0; j < 8; ++j) { s += v[j]; sq += v[j]*v[j]; }
#pragma unroll
    for (int off = 1; off < 64; off <<= 1) {
        s  += __shfl_xor(s,  off, 64);
        sq += __shfl_xor(sq, off, 64);
    }
    const float mu   = s * (1.f / CDIM);
    const float var  = sq * (1.f / CDIM) - mu * mu;
    const float rstd = rsqrtf(var + LN_EPS);

    unsigned short o[8];
#pragma unroll
    for (int j = 0; j < 8; ++j) {
        float g  = gamma[c0 + j];
        float bb = beta[c0 + j];
        o[j] = f2b((v[j] - mu) * rstd * g + bb);
    }
    uint4 pk;
    pk.x = (unsigned)o[0] | ((unsigned)o[1] << 16);
    pk.y = (unsigned)o[2] | ((unsigned)o[3] << 16);
    pk.z = (unsigned)o[4] | ((unsigned)o[5] << 16);
    pk.w = (unsigned)o[6] | ((unsigned)o[7] << 16);
    *(uint4*)(pools + (size_t)row * CDIM + c0) = pk;
}

// ---------------------------------------------------------------------------
// Kernel 2: bf16 MFMA GEMM  C[M,N] = A[M,K] * W[N,K]^T (+bias), K=512.
// R6 core: 256x256 tile, 512 threads = 8 waves (2Mx4N), wave out 128x64.
// BK=32. LDS ring: 4 slots x 32KB = 128 KB dynamic. Stage tile t+2 while
// computing t; counted s_waitcnt vmcnt(4) before each raw s_barrier.
// FRAG32=false: 8x4 frags of 16x16x32 (0 bank conflicts) for q/proj.
// FRAG32=true : 4x2 frags of 32x32x16 (R11: faster kv despite 4-way LDS
//   aliasing -- inherent to 32-row/16B-slot reads; used for kv only).
// T2 swizzle: lds_byte ^= ((lds_byte>>7)&3)<<4, realized as pre-swizzled
// GLOBAL source (stage) + swizzled ds_read address.
// Grid: 1D XCD-swizzled, N-fastest: xcd=p&7, o=p>>3, nb=o%NBLK, mb=(o/NBLK)*8+xcd.
// Epilogue: row-outer, col-inner -> output cachelines complete back-to-back.
// ---------------------------------------------------------------------------
template<bool OUT_BF16, bool BIAS, int NBLK, bool FRAG32>
__global__ __launch_bounds__(512, 2) void gemm256_kernel(
    const bf16* __restrict__ A, const bf16* __restrict__ W,
    const float* __restrict__ bias, void* __restrict__ Cptr, int Ncols)
{
    constexpr int K  = 512;
    constexpr int NT = K / 32;              // 16 K-tiles
    extern __shared__ __align__(16) char ring[];   // 4 x 32768 bytes

    const int tid = threadIdx.x;
    const int wv = tid >> 6, ln = tid & 63;
    const int wr = wv >> 2, wc = wv & 3;    // wave grid 2 (M) x 4 (N)

    const int p  = blockIdx.x;
    const int o  = p >> 3;
    const int mb = (o / NBLK) * 8 + (p & 7);
    const int nb = o % NBLK;
    const size_t m0 = (size_t)mb * 256;
    const size_t n0 = (size_t)nb * 256;

    // ---- staging (per wave: 2 instrs A + 2 instrs B per K-tile) ----
    const int srow = wv * 16 + (ln >> 2);
    const int scol = (((ln & 3) * 16) ^ (((ln >> 3) & 3) << 4)) >> 1;  // elems
    const bf16* Asrc0 = A + (m0 + srow) * K + scol;
    const bf16* Asrc1 = A + (m0 + 128 + srow) * K + scol;
    const bf16* Wsrc0 = W + (n0 + srow) * K + scol;
    const bf16* Wsrc1 = W + (n0 + 128 + srow) * K + scol;
    char* const ringc = ring;

    auto STAGE = [&](int t) {
        char* base = ringc + (t & 3) * 32768 + wv * 1024;
        const int ko = t * 32;
        lds_cp16(Asrc0 + ko, base);
        lds_cp16(Asrc1 + ko, base + 8192);
        lds_cp16(Wsrc0 + ko, base + 16384);
        lds_cp16(Wsrc1 + ko, base + 16384 + 8192);
    };

    if constexpr (!FRAG32) {
        // =================== 16x16x32 path (q / proj) ===================
        const int fr = ln & 15, kb = ln >> 4;
        const int aswz  = ((fr >> 1) & 3) << 4;
        const int a_off = (wr * 128 + fr) * 64 + ((kb * 16) ^ aswz);
        const int b_off = 16384 + (wc * 64 + fr) * 64 + ((kb * 16) ^ aswz);

        f32x4 acc[8][4];
#pragma unroll
        for (int i = 0; i < 8; ++i)
#pragma unroll
        for (int j = 0; j < 4; ++j)
            acc[i][j] = f32x4{0.f, 0.f, 0.f, 0.f};

        STAGE(0);
        STAGE(1);
        asm volatile("s_waitcnt vmcnt(4)" ::: "memory");
        __builtin_amdgcn_s_barrier();

#pragma unroll 1
        for (int t = 0; t < NT; ++t) {
            if (t + 2 < NT) STAGE(t + 2);
            const char* sa = ringc + (t & 3) * 32768;

            bf16x8 af[8], bfr[4];
#pragma unroll
            for (int mi = 0; mi < 8; ++mi)
                af[mi] = *(const bf16x8*)(sa + a_off + mi * 1024);
#pragma unroll
            for (int nj = 0; nj < 4; ++nj)
                bfr[nj] = *(const bf16x8*)(sa + b_off + nj * 1024);

#pragma unroll
            for (int mi = 0; mi < 8; ++mi)
#pragma unroll
            for (int nj = 0; nj < 4; ++nj)
                acc[mi][nj] = __builtin_amdgcn_mfma_f32_16x16x32_bf16(
                    af[mi], bfr[nj], acc[mi][nj], 0, 0, 0);

            if (t + 2 < NT) { asm volatile("s_waitcnt vmcnt(4)" ::: "memory"); }
            else            { asm volatile("s_waitcnt vmcnt(0)" ::: "memory"); }
            __builtin_amdgcn_s_barrier();
        }

        // epilogue: row = m0+wr*128+mi*16+kb*4+r ; col = n0+wc*64+nj*16+fr
        const int orow0 = wr * 128 + kb * 4;
        const int ocol0 = wc * 64 + fr;
        float bv[4];
#pragma unroll
        for (int nj = 0; nj < 4; ++nj)
            bv[nj] = BIAS ? bias[n0 + ocol0 + nj * 16] : 0.f;
#pragma unroll
        for (int mi = 0; mi < 8; ++mi) {
            const size_t rbase = m0 + orow0 + mi * 16;
#pragma unroll
            for (int r = 0; r < 4; ++r) {
                const size_t rowoff = (rbase + r) * (size_t)Ncols + n0 + ocol0;
#pragma unroll
                for (int nj = 0; nj < 4; ++nj) {
                    float v = acc[mi][nj][r] + bv[nj];
                    if (OUT_BF16)
                        ((unsigned short*)Cptr)[rowoff + nj * 16] = f2b(v);
                    else
                        ((float*)Cptr)[rowoff + nj * 16] = v;
                }
            }
        }
    } else {
        // =================== 32x32x16 path (kv) ===================
        const int lnrow = ln & 31;              // frag row (32 rows)
        const int khalf = ln >> 5;              // k-half selector
        const int swz   = (((ln & 15) >> 1) & 3) << 4;   // T2 read-side XOR
        const int a_base = (wr * 128 + lnrow) * 64;
        const int b_base = 16384 + (wc * 64 + lnrow) * 64;

        f32x16 acc[4][2];
#pragma unroll
        for (int i = 0; i < 4; ++i)
#pragma unroll
        for (int j = 0; j < 2; ++j)
#pragma unroll
            for (int e = 0; e < 16; ++e)
                acc[i][j][e] = 0.f;

        STAGE(0);
        STAGE(1);
        asm volatile("s_waitcnt vmcnt(4)" ::: "memory");
        __builtin_amdgcn_s_barrier();

#pragma unroll 1
        for (int t = 0; t < NT; ++t) {
            if (t + 2 < NT) STAGE(t + 2);
            const char* sa = ringc + (t & 3) * 32768;

            bf16x8 af[4][2], bfr[2][2];
#pragma unroll
            for (int mi = 0; mi < 4; ++mi)
#pragma unroll
                for (int ks = 0; ks < 2; ++ks)
                    af[mi][ks] = *(const bf16x8*)(sa + a_base + mi * 2048 +
                                     ((ks * 32 + khalf * 16) ^ swz));
#pragma unroll
            for (int nj = 0; nj < 2; ++nj)
#pragma unroll
                for (int ks = 0; ks < 2; ++ks)
                    bfr[nj][ks] = *(const bf16x8*)(sa + b_base + nj * 2048 +
                                     ((ks * 32 + khalf * 16) ^ swz));

#pragma unroll
            for (int mi = 0; mi < 4; ++mi)
#pragma unroll
            for (int nj = 0; nj < 2; ++nj) {
                acc[mi][nj] = __builtin_amdgcn_mfma_f32_32x32x16_bf16(
                    af[mi][0], bfr[nj][0], acc[mi][nj], 0, 0, 0);
                acc[mi][nj] = __builtin_amdgcn_mfma_f32_32x32x16_bf16(
                    af[mi][1], bfr[nj][1], acc[mi][nj], 0, 0, 0);
            }

            if (t + 2 < NT) { asm volatile("s_waitcnt vmcnt(4)" ::: "memory"); }
            else            { asm volatile("s_waitcnt vmcnt(0)" ::: "memory"); }
            __builtin_amdgcn_s_barrier();
        }

        // epilogue: row = m0+wr*128+mi*32+(reg&3)+8*(reg>>2)+4*khalf
        //           col = n0+wc*64+nj*32+lnrow
        const int ocol0 = wc * 64 + lnrow;
        float bv[2];
#pragma unroll
        for (int nj = 0; nj < 2; ++nj)
            bv[nj] = BIAS ? bias[n0 + ocol0 + nj * 32] : 0.f;
#pragma unroll
        for (int mi = 0; mi < 4; ++mi) {
            const size_t rbase = m0 + wr * 128 + mi * 32 + 4 * khalf;
#pragma unroll
            for (int r4 = 0; r4 < 4; ++r4) {
#pragma unroll
                for (int rl = 0; rl < 4; ++rl) {
                    const size_t rowoff = (rbase + rl + 8 * r4) * (size_t)Ncols
                                          + n0 + ocol0;
#pragma unroll
                    for (int nj = 0; nj < 2; ++nj) {
                        float v = acc[mi][nj][r4 * 4 + rl] + bv[nj];
                        if (OUT_BF16)
                            ((unsigned short*)Cptr)[rowoff + nj * 32] = f2b(v);
                        else
                            ((float*)Cptr)[rowoff + nj * 32] = v;
                    }
                }
            }
        }
    }
}

// ---------------------------------------------------------------------------
// Kernel 3: attention, per-batch block. 512 threads = 8 waves, wave wv = head h.
// Stage: the batch's kv slab (28 rows x 2048 B = 57 KB) is loaded cooperatively
// via global_load_lds (fully coalesced), with T2-style pre-swizzled source:
// within each row, byte c is stored at c ^ x(row), x(row)=((row&7)<<4)^(((row>>3)&3)<<5)
// (XOR is instruction-uniform, folded into per-lane source offsets). Pad rows
// 28..31 zeroed (masked rows then contribute exactly 0 in PV; no NaN hazard).
// Per wave: S = mfma(Q, K-LDS) 2x2, mask m>=28, shfl softmax over 16-lane fr
// groups, P transposed through per-wave P_t, PV = mfma(P, V^T-LDS) with
// conflict-free 2B LDS gathers (checked: K b128 ~2-way, V u16 2 lanes/dword).
// ---------------------------------------------------------------------------
__global__ __launch_bounds__(512, 2) void attn_kernel(
    const bf16* __restrict__ q, const bf16* __restrict__ kv,
    bf16* __restrict__ att)
{
    extern __shared__ __align__(16) char smem[];
    char* const kvl = smem;                                   // 64 KB (32 rows x 2 KB)
    unsigned short (*P_t)[512] = (unsigned short (*)[512])(smem + 65536);  // 8 KB

    const int tid = threadIdx.x;
    const int wv = tid >> 6, ln = tid & 63;
    const int fr = ln & 15, kb = ln >> 4;
    const int b = blockIdx.x;
    const int h = wv;

    // ---- cooperative swizzled stage of kv rows 0..27 (57344 B exact) ----
    const char* kvg = (const char*)kv + (size_t)b * (MPOOL * 2 * CDIM * 2);
#pragma unroll
    for (int i = 0; i < 7; ++i) {
        const int ob  = i * 8192 + wv * 1024;   // wave-uniform block offset
        const int row = ob >> 11;               // constant per instruction
        const int x   = ((row & 7) << 4) ^ (((row >> 3) & 3) << 5);
        const int src = ((ob & 2047) + ln * 16) ^ x;   // swizzled in-row source
        lds_cp16(kvg + (size_t)row * 2048 + src, kvl + ob);
    }
    // zero pad rows 28..31 (8 KB = 512 thr x 16 B)
    *(uint4*)(kvl + 57344 + tid * 16) = uint4{0u, 0u, 0u, 0u};
    __syncthreads();   // drains vmcnt (gload_lds) + lgkmcnt, then barrier

    // ---- Q loads direct from global (16B/lane, once) ----
    const bf16* qb = q + (size_t)b * (NTOK * CDIM) + h * HDIM;
    bf16x8 aq[2];                 // Q[fr][ks*32 + kb*8 + j]
#pragma unroll
    for (int ks = 0; ks < 2; ++ks)
        aq[ks] = *(const bf16x8*)(qb + fr * CDIM + ks * 32 + kb * 8);

    // ---- K frags from LDS: K[m][d] = row m, byte h*128 + d*2 (d<64) ----
    bf16x8 bk[2][2];              // K[mt*16+fr][ks*32 + kb*8 + j]
#pragma unroll
    for (int mt = 0; mt < 2; ++mt) {
        const int row = mt * 16 + fr;
        const int x   = ((row & 7) << 4) ^ (((row >> 3) & 3) << 5);
#pragma unroll
        for (int ks = 0; ks < 2; ++ks)
            bk[mt][ks] = *(const bf16x8*)(kvl + row * 2048 +
                              ((h * 128 + ks * 64 + kb * 16) ^ x));
    }

    // ---- V^T frags from LDS: V[m][d] = row m, byte 1024 + h*128 + d*2 ----
    bf16x8 bv[4];                 // bv[dt][j] = V[kb*8+j][dt*16+fr]
#pragma unroll
    for (int dt = 0; dt < 4; ++dt)
#pragma unroll
        for (int j = 0; j < 8; ++j) {
            const int row = kb * 8 + j;
            const int x   = ((row & 7) << 4) ^ (((row >> 3) & 3) << 5);
            bv[dt][j] = *(const short*)(kvl + row * 2048 +
                              ((1024 + h * 128 + dt * 32 + fr * 2) ^ x));
        }

    // ---- S = Q K^T (two 16x16 m-tiles, K=64) ----
    f32x4 st0 = {0.f, 0.f, 0.f, 0.f}, st1 = {0.f, 0.f, 0.f, 0.f};
    st0 = __builtin_amdgcn_mfma_f32_16x16x32_bf16(aq[0], bk[0][0], st0, 0, 0, 0);
    st0 = __builtin_amdgcn_mfma_f32_16x16x32_bf16(aq[1], bk[0][1], st0, 0, 0, 0);
    st1 = __builtin_amdgcn_mfma_f32_16x16x32_bf16(aq[0], bk[1][0], st1, 0, 0, 0);
    st1 = __builtin_amdgcn_mfma_f32_16x16x32_bf16(aq[1], bk[1][1], st1, 0, 0, 0);

    // lane holds S[n=kb*4+r][m=mt*16+fr]; scale + mask m>=28
    const bool kmask = (fr >= MPOOL - 16);
#pragma unroll
    for (int r = 0; r < 4; ++r) {
        st0[r] *= ATT_SCALE;
        st1[r] = kmask ? -1e30f : st1[r] * ATT_SCALE;
    }

    // ---- wave-parallel softmax over m (reduce across the 16-lane fr group) ----
    float p0[4], p1[4];
#pragma unroll
    for (int r = 0; r < 4; ++r) {
        float mx = fmaxf(st0[r], st1[r]);
        mx = fmaxf(mx, __shfl_xor(mx, 1, 64));
        mx = fmaxf(mx, __shfl_xor(mx, 2, 64));
        mx = fmaxf(mx, __shfl_xor(mx, 4, 64));
        mx = fmaxf(mx, __shfl_xor(mx, 8, 64));
        float e0 = expf(st0[r] - mx);
        float e1 = expf(st1[r] - mx);    // == 0 for masked lanes
        float s = e0 + e1;
        s += __shfl_xor(s, 1, 64);
        s += __shfl_xor(s, 2, 64);
        s += __shfl_xor(s, 4, 64);
        s += __shfl_xor(s, 8, 64);
        const float inv = 1.f / s;
        p0[r] = e0 * inv;
        p1[r] = e1 * inv;
    }

    // ---- transpose P via per-wave LDS: P_t[m][n], m=mt*16+fr, n=kb*4+r ----
    {
        ushort4 w0, w1;
        w0.x = f2b(p0[0]); w0.y = f2b(p0[1]); w0.z = f2b(p0[2]); w0.w = f2b(p0[3]);
        w1.x = f2b(p1[0]); w1.y = f2b(p1[1]); w1.z = f2b(p1[2]); w1.w = f2b(p1[3]);
        *(ushort4*)&P_t[wv][(fr)      * 16 + kb * 4] = w0;
        *(ushort4*)&P_t[wv][(16 + fr) * 16 + kb * 4] = w1;
    }
    asm volatile("s_waitcnt lgkmcnt(0)" ::: "memory");   // in-wave write->read

    bf16x8 pa;                    // A-frag: P[n=fr][m=kb*8+j]
#pragma unroll
    for (int j = 0; j < 8; ++j)
        pa[j] = (short)P_t[wv][(kb * 8 + j) * 16 + fr];

    // ---- O = P V  (4 d-tiles, K=32; rows m>=28 have P==0, V pad rows are 0) ----
    f32x4 o[4];
#pragma unroll
    for (int dt = 0; dt < 4; ++dt) {
        o[dt] = f32x4{0.f, 0.f, 0.f, 0.f};
        o[dt] = __builtin_amdgcn_mfma_f32_16x16x32_bf16(pa, bv[dt], o[dt], 0, 0, 0);
    }

    // ---- store: O[n=kb*4+r][d=dt*16+fr] -> att[b][n][h*64+d] ----
    unsigned short* ob = (unsigned short*)(att + (size_t)b * (NTOK * CDIM) + h * HDIM);
#pragma unroll
    for (int r = 0; r < 4; ++r) {
        const size_t nrow = (size_t)(kb * 4 + r) * CDIM;
#pragma unroll
        for (int dt = 0; dt < 4; ++dt)
            ob[nrow + dt * 16 + fr] = f2b(o[dt][r]);
    }
}

// ---------------------------------------------------------------------------
extern "C" void kernel_launch(void* const* d_in, const int* in_sizes, int n_in,
                              void* d_out, int out_size, void* d_ws, size_t ws_size,
                              hipStream_t stream)
{
    const float* x      = (const float*)d_in[0];
    const float* w_q    = (const float*)d_in[1];
    const float* w_kv   = (const float*)d_in[2];
    const float* w_proj = (const float*)d_in[3];
    const float* b_proj = (const float*)d_in[4];
    const float* gamma  = (const float*)d_in[5];
    const float* beta   = (const float*)d_in[6];

    char* ws = (char*)d_ws;
    bf16* xb    = (bf16*)(ws);
    bf16* pools = (bf16*)(ws + 67108864ull);
    bf16* qbuf  = (bf16*)(ws + 67108864ull + 117440512ull);
    bf16* kvbuf = (bf16*)(ws + 67108864ull + 117440512ull + 67108864ull);
    bf16* wqb   = (bf16*)(ws + 67108864ull + 117440512ull + 67108864ull + 234881024ull);
    bf16* wkvb  = (bf16*)((char*)wqb + 524288ull);
    bf16* wpb   = (bf16*)((char*)wkvb + 1048576ull);
    bf16* atbuf = pools;   // alias: pools dead after KV GEMM

    hipFuncSetAttribute((const void*)gemm256_kernel<true, false, 2, false>,
                        hipFuncAttributeMaxDynamicSharedMemorySize, 131072);
    hipFuncSetAttribute((const void*)gemm256_kernel<true, false, 4, true>,
                        hipFuncAttributeMaxDynamicSharedMemorySize, 131072);
    hipFuncSetAttribute((const void*)gemm256_kernel<false, true, 2, false>,
                        hipFuncAttributeMaxDynamicSharedMemorySize, 131072);
    hipFuncSetAttribute((const void*)attn_kernel,
                        hipFuncAttributeMaxDynamicSharedMemorySize, 73728);

    // 0) weight converts (single launch: w_q | w_kv | w_proj)
    convert_all_kernel<<<512, 256, 0, stream>>>(w_q, w_kv, w_proj, wqb, wkvb, wpb);

    // 1) pools + LN (+ xb emission)
    pools_ln_kernel<<<(B_SZ * MPOOL) / 4, 256, 0, stream>>>(x, gamma, beta, pools, xb);

    // 2) q = x @ w_q^T   (65536 x 512 x 512): MB=256, NBLK=2 -> grid 512
    gemm256_kernel<true, false, 2, false><<<512, 512, 131072, stream>>>(
        xb, wqb, nullptr, (void*)qbuf, 512);

    // 3) kv = pools_ln @ w_kv^T  (114688 x 1024 x 512): MB=448, NBLK=4 -> grid 1792
    gemm256_kernel<true, false, 4, true><<<1792, 512, 131072, stream>>>(
        pools, wkvb, nullptr, (void*)kvbuf, 1024);

    // 4) attention: one block per batch (8 waves = 8 heads), 73728 B dynamic LDS
    attn_kernel<<<B_SZ, 512, 73728, stream>>>(qbuf, kvbuf, atbuf);

    // 5) out = att @ w_proj^T + b_proj  (65536 x 512 x 512), fp32 out
    gemm256_kernel<false, true, 2, false><<<512, 512, 131072, stream>>>(
        atbuf, wpb, b_proj, d_out, 512);
}

// Round 14
// 413.976 us; speedup vs baseline: 1.2033x; 1.0101x over previous
//
#include <hip/hip_runtime.h>
#include <hip/hip_bf16.h>
#include <cstdint>
#include <cstddef>

// PoolingAttention.
// R19: launch-topology only (all compute paths byte-identical to R18/R14):
//  (1) convert + pools_ln merged into one launch (independent blocks).
//  (2) q GEMM + kv GEMM merged into one launch: blocks [0,512) run the q
//      template body, [512,2304) the kv body -- q's 2-round grid tail now
//      backfills with kv blocks instead of idling the chip.
// Ledger: 10 intra-GEMM variants null (164-185us), attn split neutral,
// kv+attn fusion negative. Inter-dispatch dead time is the last lever.
// R14 core: kv on 32x32x16 frags (accepted 4-way aliasing), q/proj on
// 16x16x32; GEMM = 256x256 8-wave BK=32 ring-4, counted vmcnt(4), raw
// s_barrier, T2 source-preswizzle, XCD-swizzled grid.
// R10: per-batch LDS attention (8 waves = 8 heads share staged kv slab).
// Pipeline: prep(convert|pools_ln) -> qkv GEMMs -> attention -> GEMM(proj)+bias

using bf16 = __hip_bfloat16;

#define B_SZ   4096
#define NTOK   16
#define CDIM   512
#define MPOOL  28
#define NHEAD  8
#define HDIM   64
#define LN_EPS 1e-5f
#define ATT_SCALE 0.125f

typedef short bf16x8 __attribute__((ext_vector_type(8)));
typedef float f32x4  __attribute__((ext_vector_type(4)));
typedef float f32x16 __attribute__((ext_vector_type(16)));

__constant__ int c_g1[16] = {2,3,5,6,1,4,0,7,8,9,14,15,11,12,10,13};
__constant__ int c_g2[8]  = {0,1,2,3,5,6,4,7};

__device__ __forceinline__ unsigned short f2b(float f) {
    unsigned u = __float_as_uint(f);
    return (unsigned short)((u + 0x7FFFu + ((u >> 16) & 1u)) >> 16);
}

// async global->LDS, 16B per lane; LDS dest is wave-uniform base (+lane*16 by HW)
__device__ __forceinline__ void lds_cp16(const void* g, void* l) {
    __builtin_amdgcn_global_load_lds(
        (const __attribute__((address_space(1))) void*)g,
        (__attribute__((address_space(3))) void*)l, 16, 0, 0);
}

// ---------------------------------------------------------------------------
// Kernel 1: prep = weight converts (blocks [0,512)) | pools+LN (blocks >=512).
// Convert: blocks [0,128): w_q; [128,384): w_kv; [384,512): w_proj (8 f32/thr).
// pools_ln: one wave per row; m<16 waves also emit raw-x bf16.
// ---------------------------------------------------------------------------
__global__ __launch_bounds__(256) void prep_kernel(
    const float* __restrict__ w_q, const float* __restrict__ w_kv,
    const float* __restrict__ w_proj, bf16* __restrict__ wqb,
    bf16* __restrict__ wkvb, bf16* __restrict__ wpb,
    const float* __restrict__ x, const float* __restrict__ gamma,
    const float* __restrict__ beta, bf16* __restrict__ pools,
    bf16* __restrict__ xb)
{
    if (blockIdx.x < 512) {
        // ---------------- weight convert ----------------
        const float* src; bf16* dst; int i;
        const int blk = blockIdx.x;
        if (blk < 128)      { src = w_q;    dst = wqb;  i = blk * 256 + threadIdx.x; }
        else if (blk < 384) { src = w_kv;   dst = wkvb; i = (blk - 128) * 256 + threadIdx.x; }
        else                { src = w_proj; dst = wpb;  i = (blk - 384) * 256 + threadIdx.x; }
        const float4* p = (const float4*)(src + (size_t)i * 8);
        float4 a = p[0], b = p[1];
        uint4 pk;
        pk.x = (unsigned)f2b(a.x) | ((unsigned)f2b(a.y) << 16);
        pk.y = (unsigned)f2b(a.z) | ((unsigned)f2b(a.w) << 16);
        pk.z = (unsigned)f2b(b.x) | ((unsigned)f2b(b.y) << 16);
        pk.w = (unsigned)f2b(b.z) | ((unsigned)f2b(b.w) << 16);
        *(uint4*)(dst + (size_t)i * 8) = pk;
        return;
    }

    // ---------------- pools + LayerNorm ----------------
    const int wave = threadIdx.x >> 6;
    const int lane = threadIdx.x & 63;
    const int row  = (blockIdx.x - 512) * 4 + wave;  // 0 .. B*28-1 (exact)
    const int b = row / MPOOL;
    const int m = row % MPOOL;
    const float* xb_src = x + (size_t)b * NTOK * CDIM;
    const int c0 = lane * 8;

    float v[8];
    if (m < 16) {
        const float4* p = (const float4*)(xb_src + m * CDIM + c0);
        float4 a = p[0], c = p[1];
        v[0]=a.x; v[1]=a.y; v[2]=a.z; v[3]=a.w;
        v[4]=c.x; v[5]=c.y; v[6]=c.z; v[7]=c.w;
        uint4 pk;
        pk.x = (unsigned)f2b(v[0]) | ((unsigned)f2b(v[1]) << 16);
        pk.y = (unsigned)f2b(v[2]) | ((unsigned)f2b(v[3]) << 16);
        pk.z = (unsigned)f2b(v[4]) | ((unsigned)f2b(v[5]) << 16);
        pk.w = (unsigned)f2b(v[6]) | ((unsigned)f2b(v[7]) << 16);
        *(uint4*)(xb + (size_t)b * NTOK * CDIM + (size_t)m * CDIM + c0) = pk;
    } else {
        int r0, r1;
        if (m < 24) { int j = m - 16; r0 = c_g1[2*j]; r1 = c_g1[2*j+1]; }
        else        { int j = m - 24; r0 = c_g2[2*j]; r1 = c_g2[2*j+1]; }
        const float4* p0 = (const float4*)(xb_src + r0 * CDIM + c0);
        const float4* p1 = (const float4*)(xb_src + r1 * CDIM + c0);
        float4 a0 = p0[0], a1 = p0[1];
        float4 b0 = p1[0], b1 = p1[1];
        v[0]=0.5f*(a0.x+b0.x); v[1]=0.5f*(a0.y+b0.y);
        v[2]=0.5f*(a0.z+b0.z); v[3]=0.5f*(a0.w+b0.w);
        v[4]=0.5f*(a1.x+b1.x); v[5]=0.5f*(a1.y+b1.y);
        v[6]=0.5f*(a1.z+b1.z); v[7]=0.5f*(a1.w+b1.w);
    }

    float s = 0.f, sq = 0.f;
#pragma unroll
    for (int j = 0; j < 8; ++j) { s += v[j]; sq += v[j]*v[j]; }
#pragma unroll
    for (int off = 1; off < 64; off <<= 1) {
        s  += __shfl_xor(s,  off, 64);
        sq += __shfl_xor(sq, off, 64);
    }
    const float mu   = s * (1.f / CDIM);
    const float var  = sq * (1.f / CDIM) - mu * mu;
    const float rstd = rsqrtf(var + LN_EPS);

    unsigned short o[8];
#pragma unroll
    for (int j = 0; j < 8; ++j) {
        float g  = gamma[c0 + j];
        float bb = beta[c0 + j];
        o[j] = f2b((v[j] - mu) * rstd * g + bb);
    }
    uint4 pk;
    pk.x = (unsigned)o[0] | ((unsigned)o[1] << 16);
    pk.y = (unsigned)o[2] | ((unsigned)o[3] << 16);
    pk.z = (unsigned)o[4] | ((unsigned)o[5] << 16);
    pk.w = (unsigned)o[6] | ((unsigned)o[7] << 16);
    *(uint4*)(pools + (size_t)row * CDIM + c0) = pk;
}

// ---------------------------------------------------------------------------
// GEMM body (device fn):  C[M,N] = A[M,K] * W[N,K]^T (+bias), K=512.
// R6 core: 256x256 tile, 512 threads = 8 waves (2Mx4N), wave out 128x64.
// BK=32. LDS ring: 4 slots x 32KB = 128 KB dynamic. Stage tile t+2 while
// computing t; counted s_waitcnt vmcnt(4) before each raw s_barrier.
// FRAG32=false: 8x4 frags of 16x16x32 (0 bank conflicts) for q/proj.
// FRAG32=true : 4x2 frags of 32x32x16 (R11: faster kv despite 4-way LDS
//   aliasing -- inherent to 32-row/16B-slot reads; used for kv only).
// T2 swizzle: lds_byte ^= ((lds_byte>>7)&3)<<4, realized as pre-swizzled
// GLOBAL source (stage) + swizzled ds_read address.
// Grid: 1D XCD-swizzled, N-fastest: xcd=p&7, o=p>>3, nb=o%NBLK, mb=(o/NBLK)*8+xcd.
// Epilogue: row-outer, col-inner -> output cachelines complete back-to-back.
// ---------------------------------------------------------------------------
template<bool OUT_BF16, bool BIAS, int NBLK, bool FRAG32>
__device__ __forceinline__ void gemm256_body(
    const bf16* __restrict__ A, const bf16* __restrict__ W,
    const float* __restrict__ bias, void* __restrict__ Cptr, int Ncols,
    int p, char* ringc)
{
    constexpr int K  = 512;
    constexpr int NT = K / 32;              // 16 K-tiles

    const int tid = threadIdx.x;
    const int wv = tid >> 6, ln = tid & 63;
    const int wr = wv >> 2, wc = wv & 3;    // wave grid 2 (M) x 4 (N)

    const int o  = p >> 3;
    const int mb = (o / NBLK) * 8 + (p & 7);
    const int nb = o % NBLK;
    const size_t m0 = (size_t)mb * 256;
    const size_t n0 = (size_t)nb * 256;

    // ---- staging (per wave: 2 instrs A + 2 instrs B per K-tile) ----
    const int srow = wv * 16 + (ln >> 2);
    const int scol = (((ln & 3) * 16) ^ (((ln >> 3) & 3) << 4)) >> 1;  // elems
    const bf16* Asrc0 = A + (m0 + srow) * K + scol;
    const bf16* Asrc1 = A + (m0 + 128 + srow) * K + scol;
    const bf16* Wsrc0 = W + (n0 + srow) * K + scol;
    const bf16* Wsrc1 = W + (n0 + 128 + srow) * K + scol;

    auto STAGE = [&](int t) {
        char* base = ringc + (t & 3) * 32768 + wv * 1024;
        const int ko = t * 32;
        lds_cp16(Asrc0 + ko, base);
        lds_cp16(Asrc1 + ko, base + 8192);
        lds_cp16(Wsrc0 + ko, base + 16384);
        lds_cp16(Wsrc1 + ko, base + 16384 + 8192);
    };

    if constexpr (!FRAG32) {
        // =================== 16x16x32 path (q / proj) ===================
        const int fr = ln & 15, kb = ln >> 4;
        const int aswz  = ((fr >> 1) & 3) << 4;
        const int a_off = (wr * 128 + fr) * 64 + ((kb * 16) ^ aswz);
        const int b_off = 16384 + (wc * 64 + fr) * 64 + ((kb * 16) ^ aswz);

        f32x4 acc[8][4];
#pragma unroll
        for (int i = 0; i < 8; ++i)
#pragma unroll
        for (int j = 0; j < 4; ++j)
            acc[i][j] = f32x4{0.f, 0.f, 0.f, 0.f};

        STAGE(0);
        STAGE(1);
        asm volatile("s_waitcnt vmcnt(4)" ::: "memory");
        __builtin_amdgcn_s_barrier();

#pragma unroll 1
        for (int t = 0; t < NT; ++t) {
            if (t + 2 < NT) STAGE(t + 2);
            const char* sa = ringc + (t & 3) * 32768;

            bf16x8 af[8], bfr[4];
#pragma unroll
            for (int mi = 0; mi < 8; ++mi)
                af[mi] = *(const bf16x8*)(sa + a_off + mi * 1024);
#pragma unroll
            for (int nj = 0; nj < 4; ++nj)
                bfr[nj] = *(const bf16x8*)(sa + b_off + nj * 1024);

#pragma unroll
            for (int mi = 0; mi < 8; ++mi)
#pragma unroll
            for (int nj = 0; nj < 4; ++nj)
                acc[mi][nj] = __builtin_amdgcn_mfma_f32_16x16x32_bf16(
                    af[mi], bfr[nj], acc[mi][nj], 0, 0, 0);

            if (t + 2 < NT) { asm volatile("s_waitcnt vmcnt(4)" ::: "memory"); }
            else            { asm volatile("s_waitcnt vmcnt(0)" ::: "memory"); }
            __builtin_amdgcn_s_barrier();
        }

        // epilogue: row = m0+wr*128+mi*16+kb*4+r ; col = n0+wc*64+nj*16+fr
        const int orow0 = wr * 128 + kb * 4;
        const int ocol0 = wc * 64 + fr;
        float bv[4];
#pragma unroll
        for (int nj = 0; nj < 4; ++nj)
            bv[nj] = BIAS ? bias[n0 + ocol0 + nj * 16] : 0.f;
#pragma unroll
        for (int mi = 0; mi < 8; ++mi) {
            const size_t rbase = m0 + orow0 + mi * 16;
#pragma unroll
            for (int r = 0; r < 4; ++r) {
                const size_t rowoff = (rbase + r) * (size_t)Ncols + n0 + ocol0;
#pragma unroll
                for (int nj = 0; nj < 4; ++nj) {
                    float v = acc[mi][nj][r] + bv[nj];
                    if (OUT_BF16)
                        ((unsigned short*)Cptr)[rowoff + nj * 16] = f2b(v);
                    else
                        ((float*)Cptr)[rowoff + nj * 16] = v;
                }
            }
        }
    } else {
        // =================== 32x32x16 path (kv) ===================
        const int lnrow = ln & 31;              // frag row (32 rows)
        const int khalf = ln >> 5;              // k-half selector
        const int swz   = (((ln & 15) >> 1) & 3) << 4;   // T2 read-side XOR
        const int a_base = (wr * 128 + lnrow) * 64;
        const int b_base = 16384 + (wc * 64 + lnrow) * 64;

        f32x16 acc[4][2];
#pragma unroll
        for (int i = 0; i < 4; ++i)
#pragma unroll
        for (int j = 0; j < 2; ++j)
#pragma unroll
            for (int e = 0; e < 16; ++e)
                acc[i][j][e] = 0.f;

        STAGE(0);
        STAGE(1);
        asm volatile("s_waitcnt vmcnt(4)" ::: "memory");
        __builtin_amdgcn_s_barrier();

#pragma unroll 1
        for (int t = 0; t < NT; ++t) {
            if (t + 2 < NT) STAGE(t + 2);
            const char* sa = ringc + (t & 3) * 32768;

            bf16x8 af[4][2], bfr[2][2];
#pragma unroll
            for (int mi = 0; mi < 4; ++mi)
#pragma unroll
                for (int ks = 0; ks < 2; ++ks)
                    af[mi][ks] = *(const bf16x8*)(sa + a_base + mi * 2048 +
                                     ((ks * 32 + khalf * 16) ^ swz));
#pragma unroll
            for (int nj = 0; nj < 2; ++nj)
#pragma unroll
                for (int ks = 0; ks < 2; ++ks)
                    bfr[nj][ks] = *(const bf16x8*)(sa + b_base + nj * 2048 +
                                     ((ks * 32 + khalf * 16) ^ swz));

#pragma unroll
            for (int mi = 0; mi < 4; ++mi)
#pragma unroll
            for (int nj = 0; nj < 2; ++nj) {
                acc[mi][nj] = __builtin_amdgcn_mfma_f32_32x32x16_bf16(
                    af[mi][0], bfr[nj][0], acc[mi][nj], 0, 0, 0);
                acc[mi][nj] = __builtin_amdgcn_mfma_f32_32x32x16_bf16(
                    af[mi][1], bfr[nj][1], acc[mi][nj], 0, 0, 0);
            }

            if (t + 2 < NT) { asm volatile("s_waitcnt vmcnt(4)" ::: "memory"); }
            else            { asm volatile("s_waitcnt vmcnt(0)" ::: "memory"); }
            __builtin_amdgcn_s_barrier();
        }

        // epilogue: row = m0+wr*128+mi*32+(reg&3)+8*(reg>>2)+4*khalf
        //           col = n0+wc*64+nj*32+lnrow
        const int ocol0 = wc * 64 + lnrow;
        float bv[2];
#pragma unroll
        for (int nj = 0; nj < 2; ++nj)
            bv[nj] = BIAS ? bias[n0 + ocol0 + nj * 32] : 0.f;
#pragma unroll
        for (int mi = 0; mi < 4; ++mi) {
            const size_t rbase = m0 + wr * 128 + mi * 32 + 4 * khalf;
#pragma unroll
            for (int r4 = 0; r4 < 4; ++r4) {
#pragma unroll
                for (int rl = 0; rl < 4; ++rl) {
                    const size_t rowoff = (rbase + rl + 8 * r4) * (size_t)Ncols
                                          + n0 + ocol0;
#pragma unroll
                    for (int nj = 0; nj < 2; ++nj) {
                        float v = acc[mi][nj][r4 * 4 + rl] + bv[nj];
                        if (OUT_BF16)
                            ((unsigned short*)Cptr)[rowoff + nj * 32] = f2b(v);
                        else
                            ((float*)Cptr)[rowoff + nj * 32] = v;
                    }
                }
            }
        }
    }
}

// ---------------------------------------------------------------------------
// Kernel 2: merged q + kv GEMMs. Blocks [0,512): q = xb @ w_q^T (16x16 path,
// NBLK=2, Ncols=512). Blocks [512,2304): kv = pools @ w_kv^T (32x32 path,
// NBLK=4, Ncols=1024). Independent inputs/outputs; q's grid tail backfills
// with kv blocks instead of idling CUs.
// ---------------------------------------------------------------------------
__global__ __launch_bounds__(512, 2) void qkv_gemm_kernel(
    const bf16* __restrict__ xb, const bf16* __restrict__ wqb,
    bf16* __restrict__ qbuf,
    const bf16* __restrict__ pools, const bf16* __restrict__ wkvb,
    bf16* __restrict__ kvbuf)
{
    extern __shared__ __align__(16) char ring[];   // 4 x 32768 bytes
    const int p = blockIdx.x;
    if (p < 512)
        gemm256_body<true, false, 2, false>(xb, wqb, nullptr, (void*)qbuf,
                                            512, p, ring);
    else
        gemm256_body<true, false, 4, true>(pools, wkvb, nullptr, (void*)kvbuf,
                                           1024, p - 512, ring);
}

// ---------------------------------------------------------------------------
// Kernel 4 wrapper: proj GEMM (fp32 out, bias).
// ---------------------------------------------------------------------------
__global__ __launch_bounds__(512, 2) void proj_gemm_kernel(
    const bf16* __restrict__ A, const bf16* __restrict__ W,
    const float* __restrict__ bias, float* __restrict__ C)
{
    extern __shared__ __align__(16) char ring[];
    gemm256_body<false, true, 2, false>(A, W, bias, (void*)C, 512,
                                        blockIdx.x, ring);
}

// ---------------------------------------------------------------------------
// Kernel 3: attention, per-batch block. 512 threads = 8 waves, wave wv = head h.
// Stage: the batch's kv slab (28 rows x 2048 B = 57 KB) is loaded cooperatively
// via global_load_lds (fully coalesced), with T2-style pre-swizzled source:
// within each row, byte c is stored at c ^ x(row), x(row)=((row&7)<<4)^(((row>>3)&3)<<5)
// (XOR is instruction-uniform, folded into per-lane source offsets). Pad rows
// 28..31 zeroed (masked rows then contribute exactly 0 in PV; no NaN hazard).
// Per wave: S = mfma(Q, K-LDS) 2x2, mask m>=28, shfl softmax over 16-lane fr
// groups, P transposed through per-wave P_t, PV = mfma(P, V^T-LDS) with
// conflict-free 2B LDS gathers (checked: K b128 ~2-way, V u16 2 lanes/dword).
// ---------------------------------------------------------------------------
__global__ __launch_bounds__(512, 2) void attn_kernel(
    const bf16* __restrict__ q, const bf16* __restrict__ kv,
    bf16* __restrict__ att)
{
    extern __shared__ __align__(16) char smem[];
    char* const kvl = smem;                                   // 64 KB (32 rows x 2 KB)
    unsigned short (*P_t)[512] = (unsigned short (*)[512])(smem + 65536);  // 8 KB

    const int tid = threadIdx.x;
    const int wv = tid >> 6, ln = tid & 63;
    const int fr = ln & 15, kb = ln >> 4;
    const int b = blockIdx.x;
    const int h = wv;

    // ---- cooperative swizzled stage of kv rows 0..27 (57344 B exact) ----
    const char* kvg = (const char*)kv + (size_t)b * (MPOOL * 2 * CDIM * 2);
#pragma unroll
    for (int i = 0; i < 7; ++i) {
        const int ob  = i * 8192 + wv * 1024;   // wave-uniform block offset
        const int row = ob >> 11;               // constant per instruction
        const int x   = ((row & 7) << 4) ^ (((row >> 3) & 3) << 5);
        const int src = ((ob & 2047) + ln * 16) ^ x;   // swizzled in-row source
        lds_cp16(kvg + (size_t)row * 2048 + src, kvl + ob);
    }
    // zero pad rows 28..31 (8 KB = 512 thr x 16 B)
    *(uint4*)(kvl + 57344 + tid * 16) = uint4{0u, 0u, 0u, 0u};
    __syncthreads();   // drains vmcnt (gload_lds) + lgkmcnt, then barrier

    // ---- Q loads direct from global (16B/lane, once) ----
    const bf16* qb = q + (size_t)b * (NTOK * CDIM) + h * HDIM;
    bf16x8 aq[2];                 // Q[fr][ks*32 + kb*8 + j]
#pragma unroll
    for (int ks = 0; ks < 2; ++ks)
        aq[ks] = *(const bf16x8*)(qb + fr * CDIM + ks * 32 + kb * 8);

    // ---- K frags from LDS: K[m][d] = row m, byte h*128 + d*2 (d<64) ----
    bf16x8 bk[2][2];              // K[mt*16+fr][ks*32 + kb*8 + j]
#pragma unroll
    for (int mt = 0; mt < 2; ++mt) {
        const int row = mt * 16 + fr;
        const int x   = ((row & 7) << 4) ^ (((row >> 3) & 3) << 5);
#pragma unroll
        for (int ks = 0; ks < 2; ++ks)
            bk[mt][ks] = *(const bf16x8*)(kvl + row * 2048 +
                              ((h * 128 + ks * 64 + kb * 16) ^ x));
    }

    // ---- V^T frags from LDS: V[m][d] = row m, byte 1024 + h*128 + d*2 ----
    bf16x8 bv[4];                 // bv[dt][j] = V[kb*8+j][dt*16+fr]
#pragma unroll
    for (int dt = 0; dt < 4; ++dt)
#pragma unroll
        for (int j = 0; j < 8; ++j) {
            const int row = kb * 8 + j;
            const int x   = ((row & 7) << 4) ^ (((row >> 3) & 3) << 5);
            bv[dt][j] = *(const short*)(kvl + row * 2048 +
                              ((1024 + h * 128 + dt * 32 + fr * 2) ^ x));
        }

    // ---- S = Q K^T (two 16x16 m-tiles, K=64) ----
    f32x4 st0 = {0.f, 0.f, 0.f, 0.f}, st1 = {0.f, 0.f, 0.f, 0.f};
    st0 = __builtin_amdgcn_mfma_f32_16x16x32_bf16(aq[0], bk[0][0], st0, 0, 0, 0);
    st0 = __builtin_amdgcn_mfma_f32_16x16x32_bf16(aq[1], bk[0][1], st0, 0, 0, 0);
    st1 = __builtin_amdgcn_mfma_f32_16x16x32_bf16(aq[0], bk[1][0], st1, 0, 0, 0);
    st1 = __builtin_amdgcn_mfma_f32_16x16x32_bf16(aq[1], bk[1][1], st1, 0, 0, 0);

    // lane holds S[n=kb*4+r][m=mt*16+fr]; scale + mask m>=28
    const bool kmask = (fr >= MPOOL - 16);
#pragma unroll
    for (int r = 0; r < 4; ++r) {
        st0[r] *= ATT_SCALE;
        st1[r] = kmask ? -1e30f : st1[r] * ATT_SCALE;
    }

    // ---- wave-parallel softmax over m (reduce across the 16-lane fr group) ----
    float p0[4], p1[4];
#pragma unroll
    for (int r = 0; r < 4; ++r) {
        float mx = fmaxf(st0[r], st1[r]);
        mx = fmaxf(mx, __shfl_xor(mx, 1, 64));
        mx = fmaxf(mx, __shfl_xor(mx, 2, 64));
        mx = fmaxf(mx, __shfl_xor(mx, 4, 64));
        mx = fmaxf(mx, __shfl_xor(mx, 8, 64));
        float e0 = expf(st0[r] - mx);
        float e1 = expf(st1[r] - mx);    // == 0 for masked lanes
        float s = e0 + e1;
        s += __shfl_xor(s, 1, 64);
        s += __shfl_xor(s, 2, 64);
        s += __shfl_xor(s, 4, 64);
        s += __shfl_xor(s, 8, 64);
        const float inv = 1.f / s;
        p0[r] = e0 * inv;
        p1[r] = e1 * inv;
    }

    // ---- transpose P via per-wave LDS: P_t[m][n], m=mt*16+fr, n=kb*4+r ----
    {
        ushort4 w0, w1;
        w0.x = f2b(p0[0]); w0.y = f2b(p0[1]); w0.z = f2b(p0[2]); w0.w = f2b(p0[3]);
        w1.x = f2b(p1[0]); w1.y = f2b(p1[1]); w1.z = f2b(p1[2]); w1.w = f2b(p1[3]);
        *(ushort4*)&P_t[wv][(fr)      * 16 + kb * 4] = w0;
        *(ushort4*)&P_t[wv][(16 + fr) * 16 + kb * 4] = w1;
    }
    asm volatile("s_waitcnt lgkmcnt(0)" ::: "memory");   // in-wave write->read

    bf16x8 pa;                    // A-frag: P[n=fr][m=kb*8+j]
#pragma unroll
    for (int j = 0; j < 8; ++j)
        pa[j] = (short)P_t[wv][(kb * 8 + j) * 16 + fr];

    // ---- O = P V  (4 d-tiles, K=32; rows m>=28 have P==0, V pad rows are 0) ----
    f32x4 o[4];
#pragma unroll
    for (int dt = 0; dt < 4; ++dt) {
        o[dt] = f32x4{0.f, 0.f, 0.f, 0.f};
        o[dt] = __builtin_amdgcn_mfma_f32_16x16x32_bf16(pa, bv[dt], o[dt], 0, 0, 0);
    }

    // ---- store: O[n=kb*4+r][d=dt*16+fr] -> att[b][n][h*64+d] ----
    unsigned short* ob = (unsigned short*)(att + (size_t)b * (NTOK * CDIM) + h * HDIM);
#pragma unroll
    for (int r = 0; r < 4; ++r) {
        const size_t nrow = (size_t)(kb * 4 + r) * CDIM;
#pragma unroll
        for (int dt = 0; dt < 4; ++dt)
            ob[nrow + dt * 16 + fr] = f2b(o[dt][r]);
    }
}

// ---------------------------------------------------------------------------
extern "C" void kernel_launch(void* const* d_in, const int* in_sizes, int n_in,
                              void* d_out, int out_size, void* d_ws, size_t ws_size,
                              hipStream_t stream)
{
    const float* x      = (const float*)d_in[0];
    const float* w_q    = (const float*)d_in[1];
    const float* w_kv   = (const float*)d_in[2];
    const float* w_proj = (const float*)d_in[3];
    const float* b_proj = (const float*)d_in[4];
    const float* gamma  = (const float*)d_in[5];
    const float* beta   = (const float*)d_in[6];

    char* ws = (char*)d_ws;
    bf16* xb    = (bf16*)(ws);
    bf16* pools = (bf16*)(ws + 67108864ull);
    bf16* qbuf  = (bf16*)(ws + 67108864ull + 117440512ull);
    bf16* kvbuf = (bf16*)(ws + 67108864ull + 117440512ull + 67108864ull);
    bf16* wqb   = (bf16*)(ws + 67108864ull + 117440512ull + 67108864ull + 234881024ull);
    bf16* wkvb  = (bf16*)((char*)wqb + 524288ull);
    bf16* wpb   = (bf16*)((char*)wkvb + 1048576ull);
    bf16* atbuf = pools;   // alias: pools dead after KV GEMM

    hipFuncSetAttribute((const void*)qkv_gemm_kernel,
                        hipFuncAttributeMaxDynamicSharedMemorySize, 131072);
    hipFuncSetAttribute((const void*)proj_gemm_kernel,
                        hipFuncAttributeMaxDynamicSharedMemorySize, 131072);
    hipFuncSetAttribute((const void*)attn_kernel,
                        hipFuncAttributeMaxDynamicSharedMemorySize, 73728);

    // 1) prep: weight converts (512 blocks) | pools+LN (28672 blocks)
    prep_kernel<<<512 + (B_SZ * MPOOL) / 4, 256, 0, stream>>>(
        w_q, w_kv, w_proj, wqb, wkvb, wpb, x, gamma, beta, pools, xb);

    // 2) merged q + kv GEMMs: blocks [0,512) q, [512,2304) kv
    qkv_gemm_kernel<<<512 + 1792, 512, 131072, stream>>>(
        xb, wqb, qbuf, pools, wkvb, kvbuf);

    // 3) attention: one block per batch (8 waves = 8 heads), 73728 B dynamic LDS
    attn_kernel<<<B_SZ, 512, 73728, stream>>>(qbuf, kvbuf, atbuf);

    // 4) out = att @ w_proj^T + b_proj  (65536 x 512 x 512), fp32 out
    proj_gemm_kernel<<<512, 512, 131072, stream>>>(atbuf, wpb, b_proj, (float*)d_out);
}